// Round 3
// baseline (361.654 us; speedup 1.0000x reference)
//
#include <hip/hip_runtime.h>
#include <hip/hip_bf16.h>
#include <math.h>

typedef __hip_bfloat16 bf16;
typedef __attribute__((ext_vector_type(8))) short bf16x8;
typedef __attribute__((ext_vector_type(4))) float f32x4;

#define B_  2
#define T_  2048
#define C_  2048
#define H_  16
#define HS_ 128
#define DL_ 1024
#define M_  (B_ * T_)   // 4096 tokens
#define NT64_ 32        // 32 q-tiles of 64 rows per (b,h)

// async global->LDS, 16 B per lane. LDS dest is wave-uniform base + lane*16.
__device__ inline void lds16(const bf16* g, bf16* l) {
    __builtin_amdgcn_global_load_lds(
        (const __attribute__((address_space(1))) void*)g,
        (__attribute__((address_space(3))) void*)l, 16, 0, 0);
}

// ---------------------------------------------------------------------------
// fp32 -> bf16 cast, 8 elems/thread
// ---------------------------------------------------------------------------
__global__ __launch_bounds__(256) void cast_bf16_k(
    const float* __restrict__ in, bf16* __restrict__ out)
{
    const size_t i = ((size_t)blockIdx.x * 256 + threadIdx.x) * 8;
    const float4 a = *(const float4*)(in + i);
    const float4 b = *(const float4*)(in + i + 4);
    bf16 o[8];
    o[0] = __float2bfloat16(a.x); o[1] = __float2bfloat16(a.y);
    o[2] = __float2bfloat16(a.z); o[3] = __float2bfloat16(a.w);
    o[4] = __float2bfloat16(b.x); o[5] = __float2bfloat16(b.y);
    o[6] = __float2bfloat16(b.z); o[7] = __float2bfloat16(b.w);
    *(uint4*)(out + i) = *(const uint4*)o;
}

// ---------------------------------------------------------------------------
// Fused transpose+cast of all 5 weights: blockIdx.z selects the matrix.
// ---------------------------------------------------------------------------
__global__ __launch_bounds__(256) void transpose_cast5(
    const float* __restrict__ s0, const float* __restrict__ s1,
    const float* __restrict__ s2, const float* __restrict__ s3,
    const float* __restrict__ s4,
    bf16* __restrict__ d0, bf16* __restrict__ d1, bf16* __restrict__ d2,
    bf16* __restrict__ d3, bf16* __restrict__ d4)
{
    const float* in; bf16* out; int R, Cc;
    switch (blockIdx.z) {
        case 0: in = s0; out = d0; R = C_;  Cc = C_;  break;  // Wq (C,C)
        case 1: in = s1; out = d1; R = C_;  Cc = DL_; break;  // Wc (C,DL)
        case 2: in = s2; out = d2; R = DL_; Cc = C_;  break;  // Wk (DL,C)
        case 3: in = s3; out = d3; R = DL_; Cc = C_;  break;  // Wv (DL,C)
        default: in = s4; out = d4; R = C_; Cc = C_;  break;  // Wo (C,C)
    }
    const int bx = blockIdx.x * 32, by = blockIdx.y * 32;
    if (bx >= Cc || by >= R) return;
    __shared__ float t[32][33];
    const int tx = threadIdx.x & 31, ty = threadIdx.x >> 5;
#pragma unroll
    for (int i = 0; i < 32; i += 8)
        t[ty + i][tx] = in[(size_t)(by + ty + i) * Cc + bx + tx];
    __syncthreads();
#pragma unroll
    for (int i = 0; i < 32; i += 8)
        out[(size_t)(bx + ty + i) * R + by + tx] = __float2bfloat16(t[tx][ty + i]);
}

// ---------------------------------------------------------------------------
// 256x128-tile MFMA GEMM core, 512 threads = 8 waves, BK=64,
// 3-buffer LDS ring (48 KB/buf = 144 KB), counted vmcnt(6), ONE barrier
// per K-tile (no vmcnt drain in steady state). Ring sync identical to R2
// (verified); wave mapping changed 4x2 -> 2Mx2Nx2K:
//   wave (wr, wc, kh): 128x64 output sub-tile over K-half kh (32 of 64).
//   12 ds_read_b128 + 32 MFMA per wave per K-tile (ratio 2.67 vs 2.0)
//   -> per-CU LDS 1152 cyc < MFMA 1242 cyc: MFMA becomes the floor.
// K-reduce epilogue: kh=1 waves dump acc (f32, 32 KB/wave-pair) into the
// dead ring buffers; kh=0 waves add. Linear lane*16B b128 = conflict-free.
// ---------------------------------------------------------------------------
#define GEMM250_CORE(A_, Bt_, ldA_, ldB_, Kdim_)                               \
    __shared__ __align__(16) bf16 smem[3 * 24576];   /* 144 KB */              \
    const int tid  = threadIdx.x;                                              \
    const int lane = tid & 63;                                                 \
    const int wid  = tid >> 6;                       /* 0..7 */                \
    const int kh   = wid & 1;                        /* K-half */              \
    const int wc   = (wid >> 1) & 1;                 /* N col 0..1 */          \
    const int wr   = wid >> 2;                       /* M row 0..1 */          \
    const int quad = lane >> 4, l16 = lane & 15;                               \
    const int sw8  = (l16 >> 1) & 7;                                           \
    f32x4 acc[8][4];                                                           \
    _Pragma("unroll")                                                          \
    for (int i = 0; i < 8; i++)                                                \
        _Pragma("unroll")                                                      \
        for (int j = 0; j < 4; j++) acc[i][j] = (f32x4){0.f, 0.f, 0.f, 0.f};   \
    const int sr  = tid >> 3;                        /* 0..63 */               \
    const int ssl = ((tid & 7) ^ ((sr >> 1) & 7)) * 8;                         \
    const bf16* pa = (A_)  + (size_t)(m0 + sr) * (ldA_) + ssl;                 \
    const bf16* pb = (Bt_) + (size_t)(n0 + sr) * (ldB_) + ssl;                 \
    const size_t a64 = (size_t)64 * (ldA_), b64 = (size_t)64 * (ldB_);         \
    const int NT = (Kdim_) / 64;                                               \
    _Pragma("unroll")                                                          \
    for (int pt = 0; pt < 2; ++pt) {             /* prologue: tiles 0,1 */     \
        bf16* dst = smem + pt * 24576 + tid * 8;                               \
        const size_t ko = (size_t)pt * 64;                                     \
        lds16(pa + ko,           dst);                                         \
        lds16(pa + a64 + ko,     dst + 4096);                                  \
        lds16(pa + 2*a64 + ko,   dst + 8192);                                  \
        lds16(pa + 3*a64 + ko,   dst + 12288);                                 \
        lds16(pb + ko,           dst + 16384);                                 \
        lds16(pb + b64 + ko,     dst + 20480);                                 \
    }                                                                          \
    int cur = 0, nxt2 = 2;                                                     \
    for (int t = 0; t < NT; ++t) {                                             \
        if (t == NT - 1) {                                                     \
            __asm__ __volatile__("s_waitcnt vmcnt(0)" ::: "memory");           \
        } else {                                                               \
            __asm__ __volatile__("s_waitcnt vmcnt(6)" ::: "memory");           \
        }                                                                      \
        __builtin_amdgcn_s_barrier();                                          \
        __builtin_amdgcn_sched_barrier(0);                                     \
        if (t + 2 < NT) {                                                      \
            bf16* dst = smem + nxt2 * 24576 + tid * 8;                         \
            const size_t ko = (size_t)(t + 2) * 64;                            \
            lds16(pa + ko,           dst);                                     \
            lds16(pa + a64 + ko,     dst + 4096);                              \
            lds16(pa + 2*a64 + ko,   dst + 8192);                              \
            lds16(pa + 3*a64 + ko,   dst + 12288);                             \
            lds16(pb + ko,           dst + 16384);                             \
            lds16(pb + b64 + ko,     dst + 20480);                             \
        }                                                                      \
        const bf16* Ab = smem + cur * 24576;                                   \
        const bf16* Bb = Ab + 16384;                                           \
        bf16x8 af[8], bfr[4];                                                  \
        _Pragma("unroll")                                                      \
        for (int mi = 0; mi < 8; mi++)                                         \
            af[mi] = *(const bf16x8*)&Ab[(wr*128 + mi*16 + l16)*64 +           \
                                         (((kh<<2)|quad) ^ sw8)*8];            \
        _Pragma("unroll")                                                      \
        for (int ni = 0; ni < 4; ni++)                                         \
            bfr[ni] = *(const bf16x8*)&Bb[(wc*64 + ni*16 + l16)*64 +           \
                                          (((kh<<2)|quad) ^ sw8)*8];           \
        __builtin_amdgcn_s_setprio(1);                                         \
        _Pragma("unroll")                                                      \
        for (int mi = 0; mi < 8; mi++)                                         \
            _Pragma("unroll")                                                  \
            for (int ni = 0; ni < 4; ni++)                                     \
                acc[mi][ni] = __builtin_amdgcn_mfma_f32_16x16x32_bf16(         \
                    af[mi], bfr[ni], acc[mi][ni], 0, 0, 0);                    \
        __builtin_amdgcn_s_setprio(0);                                         \
        cur  = (cur  == 2) ? 0 : cur  + 1;                                     \
        nxt2 = (nxt2 == 2) ? 0 : nxt2 + 1;                                     \
    }                                                                          \
    __syncthreads();                             /* ring dead; reuse as f32 */ \
    {                                                                          \
        float* red = (float*)smem + (size_t)((wr << 1) | wc) * 8192;           \
        if (kh) {                                                              \
            _Pragma("unroll")                                                  \
            for (int mi = 0; mi < 8; mi++)                                     \
                _Pragma("unroll")                                              \
                for (int ni = 0; ni < 4; ni++)                                 \
                    *(f32x4*)(red + (mi*4 + ni)*256 + lane*4) = acc[mi][ni];   \
        }                                                                      \
    }                                                                          \
    __syncthreads();                                                           \
    if (!kh) {                                                                 \
        const float* red = (const float*)smem + (size_t)((wr << 1) | wc) * 8192;\
        _Pragma("unroll")                                                      \
        for (int mi = 0; mi < 8; mi++)                                         \
            _Pragma("unroll")                                                  \
            for (int ni = 0; ni < 4; ni++)                                     \
                acc[mi][ni] += *(const f32x4*)(red + (mi*4 + ni)*256 + lane*4);\
    }

// ---------------------------------------------------------------------------
// Fused Q+C projection: [q | clat] = x @ [Wq | Wc], N=3072. 384 blocks.
// XCD-swizzled: xcd = lin&7 owns 3 contiguous N-panels (1.5 MB B in L2),
// M sweeps fastest within the XCD.
// ---------------------------------------------------------------------------
__global__ __launch_bounds__(512, 2) void gemm_qc_250(
    const bf16* __restrict__ A, const bf16* __restrict__ Bt,
    bf16* __restrict__ Cq, bf16* __restrict__ Cc)
{
    const int lin = blockIdx.y * 24 + blockIdx.x;    // 0..383
    const int xcd = lin & 7, ii = lin >> 3;          // ii 0..47
    const int m0 = (ii & 15) * 256;
    const int n0 = (xcd * 3 + (ii >> 4)) * 128;      // 0..23 panels
    GEMM250_CORE(A, Bt, C_, C_, C_)
    if (!kh) {
        const bool is_q = (n0 < C_);
        const float scl = is_q ? 0.08838834764831845f : 1.0f;  // 1/sqrt(128)
        bf16* dst = is_q ? Cq : Cc;
        const int ld   = is_q ? C_ : DL_;
        const int coff = is_q ? 0 : C_;
#pragma unroll
        for (int mi = 0; mi < 8; mi++) {
#pragma unroll
            for (int ni = 0; ni < 4; ni++) {
                const int col = n0 - coff + wc * 64 + ni * 16 + l16;
#pragma unroll
                for (int r = 0; r < 4; r++) {
                    const int row = m0 + wr * 128 + mi * 16 + quad * 4 + r;
                    dst[(size_t)row * ld + col] = __float2bfloat16(acc[mi][ni][r] * scl);
                }
            }
        }
    }
}

// ---------------------------------------------------------------------------
// Fused K-proj + Vt-proj (both K=1024, both consume clat): 512 blocks,
// each half XCD-swizzled (2 / 4 N-panels per XCD).
// ---------------------------------------------------------------------------
__global__ __launch_bounds__(512, 2) void gemm_kv_250(
    const bf16* __restrict__ clat, const bf16* __restrict__ Wk_t,
    const bf16* __restrict__ Wv_t, bf16* __restrict__ kk, bf16* __restrict__ vt)
{
    const int bid = blockIdx.x;
    const bf16 *A, *Bt; bf16* dst; int N, m0, n0;
    if (bid < 256) {                                 // K-proj: kk (4096,2048)
        const int xcd = bid & 7, ii = bid >> 3;      // ii 0..31
        A = clat; Bt = Wk_t; dst = kk; N = C_;
        m0 = (ii & 15) * 256;
        n0 = (xcd * 2 + (ii >> 4)) * 128;            // 0..15 panels
    } else {                                         // Vt-proj: vt (2048,4096)
        const int t2 = bid - 256;
        const int xcd = t2 & 7, ii = t2 >> 3;        // ii 0..31
        A = Wv_t; Bt = clat; dst = vt; N = M_;
        m0 = (ii & 7) * 256;
        n0 = (xcd * 4 + (ii >> 3)) * 128;            // 0..31 panels
    }
    GEMM250_CORE(A, Bt, DL_, DL_, DL_)
    if (!kh) {
#pragma unroll
        for (int mi = 0; mi < 8; mi++) {
#pragma unroll
            for (int ni = 0; ni < 4; ni++) {
                const int col = n0 + wc * 64 + ni * 16 + l16;
#pragma unroll
                for (int r = 0; r < 4; r++) {
                    const int row = m0 + wr * 128 + mi * 16 + quad * 4 + r;
                    dst[(size_t)row * N + col] = __float2bfloat16(acc[mi][ni][r]);
                }
            }
        }
    }
}

// ---------------------------------------------------------------------------
// Out-projection: out = y @ Wo_t^T + bo, fp32 out. 256 blocks (one round).
// ---------------------------------------------------------------------------
__global__ __launch_bounds__(512, 2) void gemm_out_250(
    const bf16* __restrict__ A, const bf16* __restrict__ Bt,
    float* __restrict__ Cf32, const float* __restrict__ bias)
{
    const int lin = blockIdx.y * 16 + blockIdx.x;    // 0..255
    const int xcd = lin & 7, ii = lin >> 3;          // ii 0..31
    const int m0 = (ii & 15) * 256;
    const int n0 = (xcd * 2 + (ii >> 4)) * 128;      // 0..15 panels
    GEMM250_CORE(A, Bt, C_, C_, C_)
    if (!kh) {
#pragma unroll
        for (int mi = 0; mi < 8; mi++) {
#pragma unroll
            for (int ni = 0; ni < 4; ni++) {
                const int col = n0 + wc * 64 + ni * 16 + l16;
#pragma unroll
                for (int r = 0; r < 4; r++) {
                    const int row = m0 + wr * 128 + mi * 16 + quad * 4 + r;
                    Cf32[(size_t)row * C_ + col] = acc[mi][ni][r] + bias[col];
                }
            }
        }
    }
}

// ---------------------------------------------------------------------------
// Flash attention, dual-tile, 256 threads = 4 waves, q-tiles of 64 rows.
// (unchanged this round; see R1/R2 notes)
// ---------------------------------------------------------------------------
__global__ __launch_bounds__(256, 2) void flash_dual(
    const bf16* __restrict__ Q, const bf16* __restrict__ K,
    const bf16* __restrict__ Vt, bf16* __restrict__ Y)
{
    __shared__ __align__(16) bf16 Ks[2][4][64][32];    // 32 KB (dbuf)
    __shared__ __align__(16) bf16 Vs[2][2][128][32];   // 32 KB (dbuf)
    __shared__ __align__(16) bf16 Ps[4][16][72];       // 9 KB (+8 pad)
    const int tid  = threadIdx.x;
    const int lane = tid & 63, wv = tid >> 6;          // wv 0..3
    const int quad = lane >> 4, l16 = lane & 15;
    const int sw = (l16 >> 1) & 3;
    const int bid = blockIdx.x;
    const int bh = (bid & 7) * 4 + ((bid >> 3) & 3);   // XCD-local (b,h)
    const int pa = bid >> 5;                           // 0..15
    const int b = bh >> 4, h = bh & 15;
    const int qA0 = pa * 64, qB0 = (NT64_ - 1 - pa) * 64;
    const int jA = pa + 1;
    const int jB = NT64_ - pa;                         // jA + jB = 33

    // staging: 256 threads cover 32 KB -> 8 lds16 each
    const int sr  = tid >> 2;                          // row 0..63
    const int ssl = ((tid & 3) ^ ((sr >> 1) & 3)) * 8; // swizzled 16B slot

    // Q fragments: wave rows q0 + wv*16 + l16, 4 k-chunks, both tiles
    bf16x8 qfA[4], qfB[4];
    {
        const size_t rA = (size_t)(b * T_ + qA0 + wv * 16 + l16) * C_ + h * HS_;
        const size_t rB = (size_t)(b * T_ + qB0 + wv * 16 + l16) * C_ + h * HS_;
#pragma unroll
        for (int c = 0; c < 4; c++) {
            qfA[c] = *(const bf16x8*)(Q + rA + c * 32 + quad * 8);
            qfB[c] = *(const bf16x8*)(Q + rB + c * 32 + quad * 8);
        }
    }

    f32x4 oA[8], oB[8];
#pragma unroll
    for (int dt = 0; dt < 8; dt++) {
        oA[dt] = (f32x4){0.f, 0.f, 0.f, 0.f};
        oB[dt] = (f32x4){0.f, 0.f, 0.f, 0.f};
    }
    float lA[4] = {0.f, 0.f, 0.f, 0.f}, lB[4] = {0.f, 0.f, 0.f, 0.f};
    const int rbA = qA0 + wv * 16, rbB = qB0 + wv * 16;

    auto stage = [&](int j, int sbuf) {
        const int kv0 = j * 64;
#pragma unroll
        for (int kc = 0; kc < 4; kc++)
            lds16(K + (size_t)(b * T_ + kv0 + sr) * C_ + h * HS_ + kc * 32 + ssl,
                  &Ks[sbuf][kc][0][0] + tid * 8);
#pragma unroll
        for (int vc = 0; vc < 2; vc++)
#pragma unroll
            for (int hf = 0; hf < 2; hf++)
                lds16(Vt + (size_t)(h * HS_ + hf * 64 + sr) * M_ + b * T_ + kv0 + vc * 32 + ssl,
                      &Vs[sbuf][vc][hf * 64][0] + tid * 8);
    };

    // softmax + Ps store for one 32-kv half (nt0 in {0,2}); returns PV A-frag.
    auto sm_half = [&](const f32x4* s, int nt0, float* l_s, bool diag,
                       int kv0, int rowbase) {
        float p[2][4];
#pragma unroll
        for (int t = 0; t < 2; t++)
#pragma unroll
            for (int r = 0; r < 4; r++) {
                const int nt = nt0 + t;
                float e = __expf(s[nt][r]);
                if (diag) {
                    const int col = kv0 + nt * 16 + l16;
                    const int row = rowbase + quad * 4 + r;
                    if (col > row) e = 0.f;
                }
                p[t][r] = e;
            }
#pragma unroll
        for (int r = 0; r < 4; r++) l_s[r] += p[0][r] + p[1][r];
#pragma unroll
        for (int t = 0; t < 2; t++)
#pragma unroll
            for (int r = 0; r < 4; r++)
                Ps[wv][quad * 4 + r][(nt0 + t) * 16 + l16] = __float2bfloat16(p[t][r]);
        return *(const bf16x8*)&Ps[wv][l16][nt0 * 16 + quad * 8];
    };

    stage(0, 0);

    // ---- phase 1: j in [0, jA) — both q-tiles active; kf/vf shared ----
    for (int j = 0; j < jA; j++) {
        const int kv0 = j * 64;
        stage(j + 1, (j + 1) & 1);                     // j+1 <= jA < jB always
        __asm__ __volatile__("s_waitcnt vmcnt(8)" ::: "memory");
        __builtin_amdgcn_s_barrier();
        const int buf = j & 1;

        f32x4 sA[4], sB[4];
#pragma unroll
        for (int nt = 0; nt < 4; nt++) {
            sA[nt] = (f32x4){0.f, 0.f, 0.f, 0.f};
            sB[nt] = (f32x4){0.f, 0.f, 0.f, 0.f};
        }
        __builtin_amdgcn_s_setprio(1);
#pragma unroll
        for (int c = 0; c < 4; c++) {
            bf16x8 kf[4];
#pragma unroll
            for (int nt = 0; nt < 4; nt++)
                kf[nt] = *(const bf16x8*)&Ks[buf][c][nt * 16 + l16][(quad ^ sw) * 8];
#pragma unroll
            for (int nt = 0; nt < 4; nt++) {
                sB[nt] = __builtin_amdgcn_mfma_f32_16x16x32_bf16(qfB[c], kf[nt], sB[nt], 0, 0, 0);
                sA[nt] = __builtin_amdgcn_mfma_f32_16x16x32_bf16(qfA[c], kf[nt], sA[nt], 0, 0, 0);
            }
        }
        __builtin_amdgcn_s_setprio(0);

        const bool dA = (j == jA - 1);                 // A's diagonal tile
        const bf16x8 pB0 = sm_half(sB, 0, lB, false, kv0, rbB);
        const bf16x8 pB1 = sm_half(sB, 2, lB, false, kv0, rbB);
        const bf16x8 pA0 = sm_half(sA, 0, lA, dA, kv0, rbA);
        const bf16x8 pA1 = sm_half(sA, 2, lA, dA, kv0, rbA);

        __builtin_amdgcn_s_setprio(1);
#pragma unroll
        for (int dt = 0; dt < 8; dt++) {
            const bf16x8 vf0 = *(const bf16x8*)&Vs[buf][0][dt * 16 + l16][(quad ^ sw) * 8];
            oB[dt] = __builtin_amdgcn_mfma_f32_16x16x32_bf16(pB0, vf0, oB[dt], 0, 0, 0);
            oA[dt] = __builtin_amdgcn_mfma_f32_16x16x32_bf16(pA0, vf0, oA[dt], 0, 0, 0);
        }
#pragma unroll
        for (int dt = 0; dt < 8; dt++) {
            const bf16x8 vf1 = *(const bf16x8*)&Vs[buf][1][dt * 16 + l16][(quad ^ sw) * 8];
            oB[dt] = __builtin_amdgcn_mfma_f32_16x16x32_bf16(pB1, vf1, oB[dt], 0, 0, 0);
            oA[dt] = __builtin_amdgcn_mfma_f32_16x16x32_bf16(pA1, vf1, oA[dt], 0, 0, 0);
        }
        __builtin_amdgcn_s_setprio(0);
        __asm__ __volatile__("s_waitcnt lgkmcnt(0)" ::: "memory");
        __builtin_amdgcn_s_barrier();                  // buf free for stage j+2
    }

    // ---- phase 2: j in [jA, jB) — tile B only ----
    for (int j = jA; j < jB; j++) {
        const int kv0 = j * 64;
        if (j + 1 < jB) {
            stage(j + 1, (j + 1) & 1);
            __asm__ __volatile__("s_waitcnt vmcnt(8)" ::: "memory");
        } else {
            __asm__ __volatile__("s_waitcnt vmcnt(0)" ::: "memory");
        }
        __builtin_amdgcn_s_barrier();
        const int buf = j & 1;

        f32x4 sB[4];
#pragma unroll
        for (int nt = 0; nt < 4; nt++) sB[nt] = (f32x4){0.f, 0.f, 0.f, 0.f};
        __builtin_amdgcn_s_setprio(1);
#pragma unroll
        for (int c = 0; c < 4; c++) {
            bf16x8 kf[4];
#pragma unroll
            for (int nt = 0; nt < 4; nt++)
                kf[nt] = *(const bf16x8*)&Ks[buf][c][nt * 16 + l16][(quad ^ sw) * 8];
#pragma unroll
            for (int nt = 0; nt < 4; nt++)
                sB[nt] = __builtin_amdgcn_mfma_f32_16x16x32_bf16(qfB[c], kf[nt], sB[nt], 0, 0, 0);
        }
        __builtin_amdgcn_s_setprio(0);

        const bool dB = (j == jB - 1);                 // B's diagonal tile
        const bf16x8 pB0 = sm_half(sB, 0, lB, dB, kv0, rbB);
        const bf16x8 pB1 = sm_half(sB, 2, lB, dB, kv0, rbB);

        __builtin_amdgcn_s_setprio(1);
#pragma unroll
        for (int dt = 0; dt < 8; dt++) {
            const bf16x8 vf0 = *(const bf16x8*)&Vs[buf][0][dt * 16 + l16][(quad ^ sw) * 8];
            oB[dt] = __builtin_amdgcn_mfma_f32_16x16x32_bf16(pB0, vf0, oB[dt], 0, 0, 0);
        }
#pragma unroll
        for (int dt = 0; dt < 8; dt++) {
            const bf16x8 vf1 = *(const bf16x8*)&Vs[buf][1][dt * 16 + l16][(quad ^ sw) * 8];
            oB[dt] = __builtin_amdgcn_mfma_f32_16x16x32_bf16(pB1, vf1, oB[dt], 0, 0, 0);
        }
        __builtin_amdgcn_s_setprio(0);
        __asm__ __volatile__("s_waitcnt lgkmcnt(0)" ::: "memory");
        __builtin_amdgcn_s_barrier();
    }

    // ---- epilogue: reduce l across 16-lane col group, normalize, store
    auto finish = [&](int q0, f32x4* oacc, float* l_s) {
        float inv[4];
#pragma unroll
        for (int r = 0; r < 4; r++) {
            float l = l_s[r];
            l += __shfl_xor(l, 1);
            l += __shfl_xor(l, 2);
            l += __shfl_xor(l, 4);
            l += __shfl_xor(l, 8);
            inv[r] = 1.f / l;
        }
        const int rowbase = q0 + wv * 16;
#pragma unroll
        for (int dt = 0; dt < 8; dt++)
#pragma unroll
            for (int r = 0; r < 4; r++)
                Y[(size_t)(b * T_ + rowbase + quad * 4 + r) * C_ + h * HS_ + dt * 16 + l16] =
                    __float2bfloat16(oacc[dt][r] * inv[r]);
    };
    finish(qA0, oA, lA);
    finish(qB0, oB, lB);
}

// ---------------------------------------------------------------------------
extern "C" void kernel_launch(void* const* d_in, const int* in_sizes, int n_in,
                              void* d_out, int out_size, void* d_ws, size_t ws_size,
                              hipStream_t stream) {
    const float* x  = (const float*)d_in[0];
    const float* Wq = (const float*)d_in[1];
    const float* Wc = (const float*)d_in[2];
    const float* Wk = (const float*)d_in[3];
    const float* Wv = (const float*)d_in[4];
    const float* Wo = (const float*)d_in[5];
    const float* bo = (const float*)d_in[6];
    float* out = (float*)d_out;

    bf16* ws   = (bf16*)d_ws;
    bf16* x_bf = ws;                            // (M,C)
    bf16* Wq_t = x_bf + (size_t)M_ * C_;        // (C,C)   contiguous with Wc_t
    bf16* Wc_t = Wq_t + (size_t)C_ * C_;        // (DL,C)
    bf16* Wk_t = Wc_t + (size_t)DL_ * C_;       // (C,DL)
    bf16* Wv_t = Wk_t + (size_t)C_ * DL_;       // (C,DL)
    bf16* Wo_t = Wv_t + (size_t)C_ * DL_;       // (C,C)
    bf16* q    = Wo_t + (size_t)C_ * C_;        // (M,C)  pre-scaled by 1/sqrt(HS)
    bf16* clat = q    + (size_t)M_ * C_;        // (M,DL)
    bf16* kk   = clat + (size_t)M_ * DL_;       // (M,C)
    bf16* vt   = kk   + (size_t)M_ * C_;        // (C,M)  V transposed
    bf16* y    = vt   + (size_t)C_ * M_;        // (M,C)

    const dim3 blk(256);
    const dim3 blk512(512);

    cast_bf16_k<<<dim3((M_ * C_) / (256 * 8)), blk, 0, stream>>>(x, x_bf);
    transpose_cast5<<<dim3(C_ / 32, C_ / 32, 5), blk, 0, stream>>>(
        Wq, Wc, Wk, Wv, Wo, Wq_t, Wc_t, Wk_t, Wv_t, Wo_t);

    // fused [q | clat] projection: Bt = [Wq_t ; Wc_t] (3072 x 2048)
    gemm_qc_250<<<dim3((C_ + DL_) / 128, M_ / 256), blk512, 0, stream>>>(
        x_bf, Wq_t, q, clat);
    // fused K-proj + Vt-proj (512 blocks, both K=1024)
    gemm_kv_250<<<dim3(512), blk512, 0, stream>>>(clat, Wk_t, Wv_t, kk, vt);

    flash_dual<<<dim3((NT64_ / 2) * H_ * B_), blk, 0, stream>>>(q, kk, vt, y);

    gemm_out_250<<<dim3(C_ / 128, M_ / 256), blk512, 0, stream>>>(
        y, Wo_t, out, bo);
}

// Round 4
// 345.784 us; speedup vs baseline: 1.0459x; 1.0459x over previous
//
#include <hip/hip_runtime.h>
#include <hip/hip_bf16.h>
#include <math.h>

typedef __hip_bfloat16 bf16;
typedef __attribute__((ext_vector_type(8))) short bf16x8;
typedef __attribute__((ext_vector_type(4))) float f32x4;

#define B_  2
#define T_  2048
#define C_  2048
#define H_  16
#define HS_ 128
#define DL_ 1024
#define M_  (B_ * T_)   // 4096 tokens
#define NT64_ 32        // 32 q-tiles of 64 rows per (b,h)

// async global->LDS, 16 B per lane. LDS dest is wave-uniform base + lane*16.
__device__ inline void lds16(const bf16* g, bf16* l) {
    __builtin_amdgcn_global_load_lds(
        (const __attribute__((address_space(1))) void*)g,
        (__attribute__((address_space(3))) void*)l, 16, 0, 0);
}

// ---------------------------------------------------------------------------
// fp32 -> bf16 cast, 8 elems/thread
// ---------------------------------------------------------------------------
__global__ __launch_bounds__(256) void cast_bf16_k(
    const float* __restrict__ in, bf16* __restrict__ out)
{
    const size_t i = ((size_t)blockIdx.x * 256 + threadIdx.x) * 8;
    const float4 a = *(const float4*)(in + i);
    const float4 b = *(const float4*)(in + i + 4);
    bf16 o[8];
    o[0] = __float2bfloat16(a.x); o[1] = __float2bfloat16(a.y);
    o[2] = __float2bfloat16(a.z); o[3] = __float2bfloat16(a.w);
    o[4] = __float2bfloat16(b.x); o[5] = __float2bfloat16(b.y);
    o[6] = __float2bfloat16(b.z); o[7] = __float2bfloat16(b.w);
    *(uint4*)(out + i) = *(const uint4*)o;
}

// ---------------------------------------------------------------------------
// Fused transpose+cast of all 5 weights: blockIdx.z selects the matrix.
// ---------------------------------------------------------------------------
__global__ __launch_bounds__(256) void transpose_cast5(
    const float* __restrict__ s0, const float* __restrict__ s1,
    const float* __restrict__ s2, const float* __restrict__ s3,
    const float* __restrict__ s4,
    bf16* __restrict__ d0, bf16* __restrict__ d1, bf16* __restrict__ d2,
    bf16* __restrict__ d3, bf16* __restrict__ d4)
{
    const float* in; bf16* out; int R, Cc;
    switch (blockIdx.z) {
        case 0: in = s0; out = d0; R = C_;  Cc = C_;  break;  // Wq (C,C)
        case 1: in = s1; out = d1; R = C_;  Cc = DL_; break;  // Wc (C,DL)
        case 2: in = s2; out = d2; R = DL_; Cc = C_;  break;  // Wk (DL,C)
        case 3: in = s3; out = d3; R = DL_; Cc = C_;  break;  // Wv (DL,C)
        default: in = s4; out = d4; R = C_; Cc = C_;  break;  // Wo (C,C)
    }
    const int bx = blockIdx.x * 32, by = blockIdx.y * 32;
    if (bx >= Cc || by >= R) return;
    __shared__ float t[32][33];
    const int tx = threadIdx.x & 31, ty = threadIdx.x >> 5;
#pragma unroll
    for (int i = 0; i < 32; i += 8)
        t[ty + i][tx] = in[(size_t)(by + ty + i) * Cc + bx + tx];
    __syncthreads();
#pragma unroll
    for (int i = 0; i < 32; i += 8)
        out[(size_t)(bx + ty + i) * R + by + tx] = __float2bfloat16(t[tx][ty + i]);
}

// ---------------------------------------------------------------------------
// 256x128-tile MFMA GEMM core, 512 threads = 8 waves (4Mx2N), BK=32,
// 3-buffer LDS ring (24 KB/buf = 72 KB -> 2 blocks/CU), counted vmcnt(3),
// ONE barrier per K-step (no drain in steady state).
//
// R4 change vs R2's verified BK=64 core: BK 64->32 halves the ring to 72 KB
// so TWO blocks co-reside per CU (16 waves, 4/SIMD). Two independent barrier
// chains overlap each other's staging/barrier stalls (flash_dual's trick;
// m132 lesson: occupancy > tile depth). Same ring-sync invariants as R2:
//  - wait vmcnt(3) leaves tile t+1's 3 loads in flight, confirms tile t.
//  - stage t+2 is issued after tile t's barrier (its buffer's previous
//    readers finished at the barrier ending t-1).
//  - sched_barrier(0) pins stage/reads after the barrier.
// LDS rows are 64 B (32 bf16): swizzle slot ^= (row>>1)&3 (2-way max = free;
// same form as flash's Ks swizzle). k-chunk accumulation order identical to
// BK=64 core -> bitwise-identical numerics.
// Per wave per K-step: 8 ds_read_b128 + 16 MFMA (ratio 2.0).
// ---------------------------------------------------------------------------
#define GEMM32_CORE(A_, Bt_, ldA_, ldB_, Kdim_)                                \
    __shared__ __align__(16) bf16 smem[3 * 12288];   /* 72 KB */               \
    const int tid  = threadIdx.x;                                              \
    const int lane = tid & 63;                                                 \
    const int wave = tid >> 6;                       /* 0..7 */                \
    const int wm = wave >> 1, wn = wave & 1;         /* 4Mx2N waves */         \
    const int quad = lane >> 4, l16 = lane & 15;                               \
    const int sw = (l16 >> 1) & 3;                                             \
    f32x4 acc[4][4];                                                           \
    _Pragma("unroll")                                                          \
    for (int i = 0; i < 4; i++)                                                \
        _Pragma("unroll")                                                      \
        for (int j = 0; j < 4; j++) acc[i][j] = (f32x4){0.f, 0.f, 0.f, 0.f};   \
    const int arow = tid >> 2;                       /* 0..127 */              \
    const int scol = ((tid & 3) ^ ((arow >> 1) & 3)) * 8;                      \
    const bf16* pa  = (A_)  + (size_t)(m0 + arow) * (ldA_) + scol;             \
    const bf16* pa2 = pa + (size_t)128 * (ldA_);                               \
    const bf16* pb  = (Bt_) + (size_t)(n0 + arow) * (ldB_) + scol;             \
    const int NT = (Kdim_) / 32;                                               \
    _Pragma("unroll")                                                          \
    for (int pt = 0; pt < 2; ++pt) {             /* prologue: tiles 0,1 */     \
        bf16* dst = smem + pt * 12288 + tid * 8;                               \
        const size_t ko = (size_t)pt * 32;                                     \
        lds16(pa  + ko, dst);                                                  \
        lds16(pa2 + ko, dst + 4096);                                           \
        lds16(pb  + ko, dst + 8192);                                           \
    }                                                                          \
    int cur = 0, nxt2 = 2;                                                     \
    for (int t = 0; t < NT; ++t) {                                             \
        if (t == NT - 1) {                                                     \
            __asm__ __volatile__("s_waitcnt vmcnt(0)" ::: "memory");           \
        } else {                                                               \
            __asm__ __volatile__("s_waitcnt vmcnt(3)" ::: "memory");           \
        }                                                                      \
        __builtin_amdgcn_s_barrier();                                          \
        __builtin_amdgcn_sched_barrier(0);                                     \
        if (t + 2 < NT) {                                                      \
            bf16* dst = smem + nxt2 * 12288 + tid * 8;                         \
            const size_t ko = (size_t)(t + 2) * 32;                            \
            lds16(pa  + ko, dst);                                              \
            lds16(pa2 + ko, dst + 4096);                                       \
            lds16(pb  + ko, dst + 8192);                                       \
        }                                                                      \
        const bf16* Ab = smem + cur * 12288;                                   \
        const bf16* Bb = Ab + 8192;                                            \
        bf16x8 af[4], bfr[4];                                                  \
        _Pragma("unroll")                                                      \
        for (int mi = 0; mi < 4; mi++)                                         \
            af[mi] = *(const bf16x8*)&Ab[(wm*64 + mi*16 + l16)*32 +            \
                                         ((quad ^ sw) * 8)];                   \
        _Pragma("unroll")                                                      \
        for (int ni = 0; ni < 4; ni++)                                         \
            bfr[ni] = *(const bf16x8*)&Bb[(wn*64 + ni*16 + l16)*32 +           \
                                          ((quad ^ sw) * 8)];                  \
        __builtin_amdgcn_s_setprio(1);                                         \
        _Pragma("unroll")                                                      \
        for (int mi = 0; mi < 4; mi++)                                         \
            _Pragma("unroll")                                                  \
            for (int ni = 0; ni < 4; ni++)                                     \
                acc[mi][ni] = __builtin_amdgcn_mfma_f32_16x16x32_bf16(         \
                    af[mi], bfr[ni], acc[mi][ni], 0, 0, 0);                    \
        __builtin_amdgcn_s_setprio(0);                                         \
        cur  = (cur  == 2) ? 0 : cur  + 1;                                     \
        nxt2 = (nxt2 == 2) ? 0 : nxt2 + 1;                                     \
    }

// ---------------------------------------------------------------------------
// Fused Q+C projection: [q | clat] = x @ [Wq | Wc], N=3072. 384 blocks,
// natural order (n fastest): XCDs stay in M-lockstep -> A rows L3-shared.
// ---------------------------------------------------------------------------
__global__ __launch_bounds__(512, 4) void gemm_qc_250(
    const bf16* __restrict__ A, const bf16* __restrict__ Bt,
    bf16* __restrict__ Cq, bf16* __restrict__ Cc)
{
    const int m0 = blockIdx.y * 256, n0 = blockIdx.x * 128;
    GEMM32_CORE(A, Bt, C_, C_, C_)
    const bool is_q = (n0 < C_);
    const float scl = is_q ? 0.08838834764831845f : 1.0f;   // 1/sqrt(128)
    bf16* dst = is_q ? Cq : Cc;
    const int ld   = is_q ? C_ : DL_;
    const int coff = is_q ? 0 : C_;
#pragma unroll
    for (int mi = 0; mi < 4; mi++) {
#pragma unroll
        for (int ni = 0; ni < 4; ni++) {
            const int col = n0 - coff + wn * 64 + ni * 16 + l16;
#pragma unroll
            for (int r = 0; r < 4; r++) {
                const int row = m0 + wm * 64 + mi * 16 + quad * 4 + r;
                dst[(size_t)row * ld + col] = __float2bfloat16(acc[mi][ni][r] * scl);
            }
        }
    }
}

// ---------------------------------------------------------------------------
// Fused K-proj + Vt-proj (both K=1024, both consume clat): 512 blocks
// = exactly 2 blocks/CU in one scheduling wave.
// ---------------------------------------------------------------------------
__global__ __launch_bounds__(512, 4) void gemm_kv_250(
    const bf16* __restrict__ clat, const bf16* __restrict__ Wk_t,
    const bf16* __restrict__ Wv_t, bf16* __restrict__ kk, bf16* __restrict__ vt)
{
    const int bid = blockIdx.x;
    const bf16 *A, *Bt; bf16* dst; int N, m0, n0;
    if (bid < 256) { A = clat; Bt = Wk_t; dst = kk; N = C_;
                     m0 = (bid >> 4) * 256; n0 = (bid & 15) * 128; }
    else           { const int t2 = bid - 256;
                     A = Wv_t; Bt = clat; dst = vt; N = M_;
                     m0 = (t2 >> 5) * 256; n0 = (t2 & 31) * 128; }
    GEMM32_CORE(A, Bt, DL_, DL_, DL_)
#pragma unroll
    for (int mi = 0; mi < 4; mi++) {
#pragma unroll
        for (int ni = 0; ni < 4; ni++) {
            const int col = n0 + wn * 64 + ni * 16 + l16;
#pragma unroll
            for (int r = 0; r < 4; r++) {
                const int row = m0 + wm * 64 + mi * 16 + quad * 4 + r;
                dst[(size_t)row * N + col] = __float2bfloat16(acc[mi][ni][r]);
            }
        }
    }
}

// ---------------------------------------------------------------------------
// Out-projection: out = y @ Wo_t^T + bo, fp32 out. 256 blocks.
// ---------------------------------------------------------------------------
__global__ __launch_bounds__(512, 4) void gemm_out_250(
    const bf16* __restrict__ A, const bf16* __restrict__ Bt,
    float* __restrict__ Cf32, const float* __restrict__ bias)
{
    const int m0 = blockIdx.y * 256, n0 = blockIdx.x * 128;
    GEMM32_CORE(A, Bt, C_, C_, C_)
#pragma unroll
    for (int mi = 0; mi < 4; mi++) {
#pragma unroll
        for (int ni = 0; ni < 4; ni++) {
            const int col = n0 + wn * 64 + ni * 16 + l16;
#pragma unroll
            for (int r = 0; r < 4; r++) {
                const int row = m0 + wm * 64 + mi * 16 + quad * 4 + r;
                Cf32[(size_t)row * C_ + col] = acc[mi][ni][r] + bias[col];
            }
        }
    }
}

// ---------------------------------------------------------------------------
// Flash attention, dual-tile, 256 threads = 4 waves, q-tiles of 64 rows.
// (unchanged; see R1/R2 notes)
// ---------------------------------------------------------------------------
__global__ __launch_bounds__(256, 2) void flash_dual(
    const bf16* __restrict__ Q, const bf16* __restrict__ K,
    const bf16* __restrict__ Vt, bf16* __restrict__ Y)
{
    __shared__ __align__(16) bf16 Ks[2][4][64][32];    // 32 KB (dbuf)
    __shared__ __align__(16) bf16 Vs[2][2][128][32];   // 32 KB (dbuf)
    __shared__ __align__(16) bf16 Ps[4][16][72];       // 9 KB (+8 pad)
    const int tid  = threadIdx.x;
    const int lane = tid & 63, wv = tid >> 6;          // wv 0..3
    const int quad = lane >> 4, l16 = lane & 15;
    const int sw = (l16 >> 1) & 3;
    const int bid = blockIdx.x;
    const int bh = (bid & 7) * 4 + ((bid >> 3) & 3);   // XCD-local (b,h)
    const int pa = bid >> 5;                           // 0..15
    const int b = bh >> 4, h = bh & 15;
    const int qA0 = pa * 64, qB0 = (NT64_ - 1 - pa) * 64;
    const int jA = pa + 1;
    const int jB = NT64_ - pa;                         // jA + jB = 33

    // staging: 256 threads cover 32 KB -> 8 lds16 each
    const int sr  = tid >> 2;                          // row 0..63
    const int ssl = ((tid & 3) ^ ((sr >> 1) & 3)) * 8; // swizzled 16B slot

    // Q fragments: wave rows q0 + wv*16 + l16, 4 k-chunks, both tiles
    bf16x8 qfA[4], qfB[4];
    {
        const size_t rA = (size_t)(b * T_ + qA0 + wv * 16 + l16) * C_ + h * HS_;
        const size_t rB = (size_t)(b * T_ + qB0 + wv * 16 + l16) * C_ + h * HS_;
#pragma unroll
        for (int c = 0; c < 4; c++) {
            qfA[c] = *(const bf16x8*)(Q + rA + c * 32 + quad * 8);
            qfB[c] = *(const bf16x8*)(Q + rB + c * 32 + quad * 8);
        }
    }

    f32x4 oA[8], oB[8];
#pragma unroll
    for (int dt = 0; dt < 8; dt++) {
        oA[dt] = (f32x4){0.f, 0.f, 0.f, 0.f};
        oB[dt] = (f32x4){0.f, 0.f, 0.f, 0.f};
    }
    float lA[4] = {0.f, 0.f, 0.f, 0.f}, lB[4] = {0.f, 0.f, 0.f, 0.f};
    const int rbA = qA0 + wv * 16, rbB = qB0 + wv * 16;

    auto stage = [&](int j, int sbuf) {
        const int kv0 = j * 64;
#pragma unroll
        for (int kc = 0; kc < 4; kc++)
            lds16(K + (size_t)(b * T_ + kv0 + sr) * C_ + h * HS_ + kc * 32 + ssl,
                  &Ks[sbuf][kc][0][0] + tid * 8);
#pragma unroll
        for (int vc = 0; vc < 2; vc++)
#pragma unroll
            for (int hf = 0; hf < 2; hf++)
                lds16(Vt + (size_t)(h * HS_ + hf * 64 + sr) * M_ + b * T_ + kv0 + vc * 32 + ssl,
                      &Vs[sbuf][vc][hf * 64][0] + tid * 8);
    };

    // softmax + Ps store for one 32-kv half (nt0 in {0,2}); returns PV A-frag.
    auto sm_half = [&](const f32x4* s, int nt0, float* l_s, bool diag,
                       int kv0, int rowbase) {
        float p[2][4];
#pragma unroll
        for (int t = 0; t < 2; t++)
#pragma unroll
            for (int r = 0; r < 4; r++) {
                const int nt = nt0 + t;
                float e = __expf(s[nt][r]);
                if (diag) {
                    const int col = kv0 + nt * 16 + l16;
                    const int row = rowbase + quad * 4 + r;
                    if (col > row) e = 0.f;
                }
                p[t][r] = e;
            }
#pragma unroll
        for (int r = 0; r < 4; r++) l_s[r] += p[0][r] + p[1][r];
#pragma unroll
        for (int t = 0; t < 2; t++)
#pragma unroll
            for (int r = 0; r < 4; r++)
                Ps[wv][quad * 4 + r][(nt0 + t) * 16 + l16] = __float2bfloat16(p[t][r]);
        return *(const bf16x8*)&Ps[wv][l16][nt0 * 16 + quad * 8];
    };

    stage(0, 0);

    // ---- phase 1: j in [0, jA) — both q-tiles active; kf/vf shared ----
    for (int j = 0; j < jA; j++) {
        const int kv0 = j * 64;
        stage(j + 1, (j + 1) & 1);                     // j+1 <= jA < jB always
        __asm__ __volatile__("s_waitcnt vmcnt(8)" ::: "memory");
        __builtin_amdgcn_s_barrier();
        const int buf = j & 1;

        f32x4 sA[4], sB[4];
#pragma unroll
        for (int nt = 0; nt < 4; nt++) {
            sA[nt] = (f32x4){0.f, 0.f, 0.f, 0.f};
            sB[nt] = (f32x4){0.f, 0.f, 0.f, 0.f};
        }
        __builtin_amdgcn_s_setprio(1);
#pragma unroll
        for (int c = 0; c < 4; c++) {
            bf16x8 kf[4];
#pragma unroll
            for (int nt = 0; nt < 4; nt++)
                kf[nt] = *(const bf16x8*)&Ks[buf][c][nt * 16 + l16][(quad ^ sw) * 8];
#pragma unroll
            for (int nt = 0; nt < 4; nt++) {
                sB[nt] = __builtin_amdgcn_mfma_f32_16x16x32_bf16(qfB[c], kf[nt], sB[nt], 0, 0, 0);
                sA[nt] = __builtin_amdgcn_mfma_f32_16x16x32_bf16(qfA[c], kf[nt], sA[nt], 0, 0, 0);
            }
        }
        __builtin_amdgcn_s_setprio(0);

        const bool dA = (j == jA - 1);                 // A's diagonal tile
        const bf16x8 pB0 = sm_half(sB, 0, lB, false, kv0, rbB);
        const bf16x8 pB1 = sm_half(sB, 2, lB, false, kv0, rbB);
        const bf16x8 pA0 = sm_half(sA, 0, lA, dA, kv0, rbA);
        const bf16x8 pA1 = sm_half(sA, 2, lA, dA, kv0, rbA);

        __builtin_amdgcn_s_setprio(1);
#pragma unroll
        for (int dt = 0; dt < 8; dt++) {
            const bf16x8 vf0 = *(const bf16x8*)&Vs[buf][0][dt * 16 + l16][(quad ^ sw) * 8];
            oB[dt] = __builtin_amdgcn_mfma_f32_16x16x32_bf16(pB0, vf0, oB[dt], 0, 0, 0);
            oA[dt] = __builtin_amdgcn_mfma_f32_16x16x32_bf16(pA0, vf0, oA[dt], 0, 0, 0);
        }
#pragma unroll
        for (int dt = 0; dt < 8; dt++) {
            const bf16x8 vf1 = *(const bf16x8*)&Vs[buf][1][dt * 16 + l16][(quad ^ sw) * 8];
            oB[dt] = __builtin_amdgcn_mfma_f32_16x16x32_bf16(pB1, vf1, oB[dt], 0, 0, 0);
            oA[dt] = __builtin_amdgcn_mfma_f32_16x16x32_bf16(pA1, vf1, oA[dt], 0, 0, 0);
        }
        __builtin_amdgcn_s_setprio(0);
        __asm__ __volatile__("s_waitcnt lgkmcnt(0)" ::: "memory");
        __builtin_amdgcn_s_barrier();                  // buf free for stage j+2
    }

    // ---- phase 2: j in [jA, jB) — tile B only ----
    for (int j = jA; j < jB; j++) {
        const int kv0 = j * 64;
        if (j + 1 < jB) {
            stage(j + 1, (j + 1) & 1);
            __asm__ __volatile__("s_waitcnt vmcnt(8)" ::: "memory");
        } else {
            __asm__ __volatile__("s_waitcnt vmcnt(0)" ::: "memory");
        }
        __builtin_amdgcn_s_barrier();
        const int buf = j & 1;

        f32x4 sB[4];
#pragma unroll
        for (int nt = 0; nt < 4; nt++) sB[nt] = (f32x4){0.f, 0.f, 0.f, 0.f};
        __builtin_amdgcn_s_setprio(1);
#pragma unroll
        for (int c = 0; c < 4; c++) {
            bf16x8 kf[4];
#pragma unroll
            for (int nt = 0; nt < 4; nt++)
                kf[nt] = *(const bf16x8*)&Ks[buf][c][nt * 16 + l16][(quad ^ sw) * 8];
#pragma unroll
            for (int nt = 0; nt < 4; nt++)
                sB[nt] = __builtin_amdgcn_mfma_f32_16x16x32_bf16(qfB[c], kf[nt], sB[nt], 0, 0, 0);
        }
        __builtin_amdgcn_s_setprio(0);

        const bool dB = (j == jB - 1);                 // B's diagonal tile
        const bf16x8 pB0 = sm_half(sB, 0, lB, dB, kv0, rbB);
        const bf16x8 pB1 = sm_half(sB, 2, lB, dB, kv0, rbB);

        __builtin_amdgcn_s_setprio(1);
#pragma unroll
        for (int dt = 0; dt < 8; dt++) {
            const bf16x8 vf0 = *(const bf16x8*)&Vs[buf][0][dt * 16 + l16][(quad ^ sw) * 8];
            oB[dt] = __builtin_amdgcn_mfma_f32_16x16x32_bf16(pB0, vf0, oB[dt], 0, 0, 0);
        }
#pragma unroll
        for (int dt = 0; dt < 8; dt++) {
            const bf16x8 vf1 = *(const bf16x8*)&Vs[buf][1][dt * 16 + l16][(quad ^ sw) * 8];
            oB[dt] = __builtin_amdgcn_mfma_f32_16x16x32_bf16(pB1, vf1, oB[dt], 0, 0, 0);
        }
        __builtin_amdgcn_s_setprio(0);
        __asm__ __volatile__("s_waitcnt lgkmcnt(0)" ::: "memory");
        __builtin_amdgcn_s_barrier();
    }

    // ---- epilogue: reduce l across 16-lane col group, normalize, store
    auto finish = [&](int q0, f32x4* oacc, float* l_s) {
        float inv[4];
#pragma unroll
        for (int r = 0; r < 4; r++) {
            float l = l_s[r];
            l += __shfl_xor(l, 1);
            l += __shfl_xor(l, 2);
            l += __shfl_xor(l, 4);
            l += __shfl_xor(l, 8);
            inv[r] = 1.f / l;
        }
        const int rowbase = q0 + wv * 16;
#pragma unroll
        for (int dt = 0; dt < 8; dt++)
#pragma unroll
            for (int r = 0; r < 4; r++)
                Y[(size_t)(b * T_ + rowbase + quad * 4 + r) * C_ + h * HS_ + dt * 16 + l16] =
                    __float2bfloat16(oacc[dt][r] * inv[r]);
    };
    finish(qA0, oA, lA);
    finish(qB0, oB, lB);
}

// ---------------------------------------------------------------------------
extern "C" void kernel_launch(void* const* d_in, const int* in_sizes, int n_in,
                              void* d_out, int out_size, void* d_ws, size_t ws_size,
                              hipStream_t stream) {
    const float* x  = (const float*)d_in[0];
    const float* Wq = (const float*)d_in[1];
    const float* Wc = (const float*)d_in[2];
    const float* Wk = (const float*)d_in[3];
    const float* Wv = (const float*)d_in[4];
    const float* Wo = (const float*)d_in[5];
    const float* bo = (const float*)d_in[6];
    float* out = (float*)d_out;

    bf16* ws   = (bf16*)d_ws;
    bf16* x_bf = ws;                            // (M,C)
    bf16* Wq_t = x_bf + (size_t)M_ * C_;        // (C,C)   contiguous with Wc_t
    bf16* Wc_t = Wq_t + (size_t)C_ * C_;        // (DL,C)
    bf16* Wk_t = Wc_t + (size_t)DL_ * C_;       // (C,DL)
    bf16* Wv_t = Wk_t + (size_t)C_ * DL_;       // (C,DL)
    bf16* Wo_t = Wv_t + (size_t)C_ * DL_;       // (C,C)
    bf16* q    = Wo_t + (size_t)C_ * C_;        // (M,C)  pre-scaled by 1/sqrt(HS)
    bf16* clat = q    + (size_t)M_ * C_;        // (M,DL)
    bf16* kk   = clat + (size_t)M_ * DL_;       // (M,C)
    bf16* vt   = kk   + (size_t)M_ * C_;        // (C,M)  V transposed
    bf16* y    = vt   + (size_t)C_ * M_;        // (M,C)

    const dim3 blk(256);
    const dim3 blk512(512);

    cast_bf16_k<<<dim3((M_ * C_) / (256 * 8)), blk, 0, stream>>>(x, x_bf);
    transpose_cast5<<<dim3(C_ / 32, C_ / 32, 5), blk, 0, stream>>>(
        Wq, Wc, Wk, Wv, Wo, Wq_t, Wc_t, Wk_t, Wv_t, Wo_t);

    // fused [q | clat] projection: Bt = [Wq_t ; Wc_t] (3072 x 2048)
    gemm_qc_250<<<dim3((C_ + DL_) / 128, M_ / 256), blk512, 0, stream>>>(
        x_bf, Wq_t, q, clat);
    // fused K-proj + Vt-proj (512 blocks = exactly 2/CU, both K=1024)
    gemm_kv_250<<<dim3(512), blk512, 0, stream>>>(clat, Wk_t, Wv_t, kk, vt);

    flash_dual<<<dim3((NT64_ / 2) * H_ * B_), blk, 0, stream>>>(q, kk, vt, y);

    gemm_out_250<<<dim3(C_ / 128, M_ / 256), blk512, 0, stream>>>(
        y, Wo_t, out, bo);
}